// Round 5
// baseline (349.944 us; speedup 1.0000x reference)
//
#include <hip/hip_runtime.h>
#include <stdint.h>

typedef unsigned short u16;
typedef unsigned int u32;
typedef __bf16 bf16x8 __attribute__((ext_vector_type(8)));
typedef float f32x4 __attribute__((ext_vector_type(4)));

#define QSCALE 0.1803368801111244f   // 64^-0.5 * log2(e): S comes out in log2 domain
#define M0 18.0f                     // fixed softmax "max" in log2 domain (true |s| <~ 12)

// ---------- helpers ----------
__device__ __forceinline__ u16 f2bf(float f) {
  union { float f; unsigned u; } v; v.f = f;
  return (u16)((v.u + 0x7FFFu + ((v.u >> 16) & 1u)) >> 16);
}

__device__ __forceinline__ void gl_lds16(const void* g, void* l) {
  typedef __attribute__((address_space(1))) void* gp_t;
  typedef __attribute__((address_space(3))) void* lp_t;
  __builtin_amdgcn_global_load_lds((gp_t)(g), (lp_t)(l), 16, 0, 0);
}

union BF8 { u32 u[4]; bf16x8 v; };
union FU { float f; u32 u; };

// ---------- fp32 -> bf16 converts ----------
__global__ void __launch_bounds__(256) cvt_f32_bf16(const float* __restrict__ in,
                                                    u16* __restrict__ out, int n) {
  int i = (blockIdx.x * 256 + threadIdx.x) * 4;
  if (i < n) {
    float4 f = *(const float4*)(in + i);
    ushort4 o;
    o.x = f2bf(f.x); o.y = f2bf(f.y); o.z = f2bf(f.z); o.w = f2bf(f.w);
    *(ushort4*)(out + i) = o;
  }
}

// 4 weight matrices (1M elements each) -> contiguous bf16 dst
__global__ void __launch_bounds__(256) cvt_w4(const float* __restrict__ a,
                                              const float* __restrict__ b,
                                              const float* __restrict__ c,
                                              const float* __restrict__ d,
                                              u16* __restrict__ out) {
  int i = (blockIdx.x * 256 + threadIdx.x) * 4;
  int sel = i >> 20;
  const float* src = (sel == 0) ? a : (sel == 1) ? b : (sel == 2) ? c : d;
  float4 f = *(const float4*)(src + (i & 1048575));
  ushort4 o;
  o.x = f2bf(f.x); o.y = f2bf(f.y); o.z = f2bf(f.z); o.w = f2bf(f.w);
  *(ushort4*)(out + i) = o;
}

// ---------- pipelined MT x NT GEMM core: C = A @ W^T, K=1024, BK=64 ----------
// Tensile-style: global->VGPR prefetch (2-deep, ping-pong reg sets) + ds_write into
// double-buffered LDS. Barriers need only lgkmcnt(0); global loads stay in flight
// across them (the m97 vmcnt(0)-drain stall is gone). XOR-swizzled LDS as before.
template <int MT, int NT>
__device__ __forceinline__ void gemm_pipe(const u16* __restrict__ A, const u16* __restrict__ W,
                                          u16* __restrict__ lds,   // 2*(MT+NT)*64 u16
                                          f32x4 (&acc)[MT / 32][NT / 32],
                                          int m0, int n0) {
  constexpr int AG = MT / 32, BG = NT / 32;
  constexpr int ASZ = MT * 64, BSZ = NT * 64;
  u16* As[2] = { lds, lds + ASZ + BSZ };
  u16* Bs[2] = { lds + ASZ, lds + 2 * ASZ + BSZ };
  const int tid = threadIdx.x, w = tid >> 6, lane = tid & 63;
  const int wm = (w >> 1) * (MT / 2), wn = (w & 1) * (NT / 2);
  const int q4 = lane >> 4, c = lane & 15;

  // staging assignment: chunk g = qq*256 + tid -> row = g>>3, kchunk = g&7
  size_t aga[AG], bga[BG];   // global element offsets (k0 added per tile)
  int    ало_dummy = 0; (void)ало_dummy;
  int    alo[AG], blo[BG];   // LDS u16 offsets (swizzled)
#pragma unroll
  for (int qq = 0; qq < AG; ++qq) {
    int g = qq * 256 + tid, row = g >> 3, kc = g & 7;
    aga[qq] = (size_t)(m0 + row) * 1024 + kc * 8;
    alo[qq] = row * 64 + ((kc ^ (row & 7)) * 8);
  }
#pragma unroll
  for (int qq = 0; qq < BG; ++qq) {
    int g = qq * 256 + tid, row = g >> 3, kc = g & 7;
    bga[qq] = (size_t)(n0 + row) * 1024 + kc * 8;
    blo[qq] = row * 64 + ((kc ^ (row & 7)) * 8);
  }

  int4 ar[2][AG], br[2][BG];   // ping-pong prefetch registers

#define LOAD_TILE(s, k0)                                            \
  {                                                                 \
    _Pragma("unroll") for (int qq = 0; qq < AG; ++qq)               \
        ar[s][qq] = *(const int4*)(A + aga[qq] + (k0));             \
    _Pragma("unroll") for (int qq = 0; qq < BG; ++qq)               \
        br[s][qq] = *(const int4*)(W + bga[qq] + (k0));             \
  }
#define WRITE_TILE(s, d)                                            \
  {                                                                 \
    _Pragma("unroll") for (int qq = 0; qq < AG; ++qq)               \
        *(int4*)(As[d] + alo[qq]) = ar[s][qq];                      \
    _Pragma("unroll") for (int qq = 0; qq < BG; ++qq)               \
        *(int4*)(Bs[d] + blo[qq]) = br[s][qq];                      \
  }

  LOAD_TILE(0, 0)
  LOAD_TILE(1, 64)
  WRITE_TILE(0, 0)
  __syncthreads();

#pragma unroll
  for (int kt = 0; kt < 16; ++kt) {
    const int cur = kt & 1;
    if (kt < 14) LOAD_TILE(cur, (kt + 2) * 64)          // tile kt+2 -> set[cur]
    // compute tile kt from buf[cur]
#pragma unroll
    for (int ks = 0; ks < 2; ++ks) {
      bf16x8 af[AG], bfr[BG];
#pragma unroll
      for (int i = 0; i < AG; ++i) {
        int row = wm + i * 16 + c;
        af[i] = *(const bf16x8*)(As[cur] + row * 64 + (((ks * 4 + q4) ^ (row & 7)) * 8));
      }
#pragma unroll
      for (int j = 0; j < BG; ++j) {
        int row = wn + j * 16 + c;
        bfr[j] = *(const bf16x8*)(Bs[cur] + row * 64 + (((ks * 4 + q4) ^ (row & 7)) * 8));
      }
#pragma unroll
      for (int i = 0; i < AG; ++i)
#pragma unroll
        for (int j = 0; j < BG; ++j)
          acc[i][j] = __builtin_amdgcn_mfma_f32_16x16x32_bf16(af[i], bfr[j], acc[i][j], 0, 0, 0);
    }
    if (kt < 15) {
      WRITE_TILE(1 - cur, 1 - cur)                      // tile kt+1 -> buf[1-cur]
      __syncthreads();
    }
  }
#undef LOAD_TILE
#undef WRITE_TILE
}

// ---------- fused QKV projection: one GEMM vs [Wq;Wk;Wv] (N=3072), tile 128x64 ----------
// n0>>10 selects output: 0 -> Q (pre-scaled), 1 -> K, 2 -> V^T sigma-permuted.
__global__ void __launch_bounds__(256) qkv_gemm(const u16* __restrict__ Hb,
                                                const u16* __restrict__ Wqkv,
                                                u16* __restrict__ Q, u16* __restrict__ K,
                                                u16* __restrict__ Vt) {
  __shared__ u16 lds[2 * (128 + 64) * 64];   // 48 KiB
  f32x4 acc[4][2];
#pragma unroll
  for (int i = 0; i < 4; ++i)
#pragma unroll
    for (int j = 0; j < 2; ++j) { f32x4 zv = {0.f, 0.f, 0.f, 0.f}; acc[i][j] = zv; }

  const int m0 = blockIdx.y * 128, n0g = blockIdx.x * 64;
  gemm_pipe<128, 64>(Hb, Wqkv, lds, acc, m0, n0g);

  const int z = n0g >> 10, nl0 = n0g & 1023;
  const int tid = threadIdx.x, w = tid >> 6, lane = tid & 63;
  const int wm = (w >> 1) * 64, wn = (w & 1) * 32;
  const int q4 = lane >> 4, c = lane & 15;

#pragma unroll
  for (int i = 0; i < 4; ++i)
#pragma unroll
    for (int j = 0; j < 2; ++j)
#pragma unroll
      for (int r = 0; r < 4; ++r) {
        int m = m0 + wm + i * 16 + q4 * 4 + r;       // b*2048 + s
        int n = nl0 + wn + j * 16 + c;               // h*64 + d (within 1024)
        if (z == 0) {
          Q[(size_t)m * 1024 + n] = f2bf(acc[i][j][r] * QSCALE);
        } else if (z == 1) {
          K[(size_t)m * 1024 + n] = f2bf(acc[i][j][r]);
        } else {
          int b = m >> 11, s = m & 2047, h = n >> 6, d = n & 63;
          int kv = s & 127;
          int sig = ((kv >> 5) << 5) | (((kv >> 2) & 3) << 3) | (((kv >> 4) & 1) << 2) | (kv & 3);
          int sp = (s & ~127) | sig;
          Vt[(((size_t)(b * 16 + h) * 64 + d) << 11) + sp] = f2bf(acc[i][j][r]);
        }
      }
}

// ---------- flash attention, S^T orientation, fixed-max streaming softmax ----------
// (unchanged from round 4)
__global__ void __launch_bounds__(256, 2) attn(const u16* __restrict__ Q, const u16* __restrict__ K,
                                               const u16* __restrict__ Vt, u16* __restrict__ O) {
  __shared__ u16 Ks[128 * 64];   // [kv 128][d 64], swizzled (8 chunks/row)
  __shared__ u16 Vs[64 * 128];   // [d 64][kv' 128], swizzled (16 chunks/row)

  const int tid = threadIdx.x, w = tid >> 6, lane = tid & 63;
  const int q4 = lane >> 4, c = lane & 15;
  const int qt = blockIdx.x;                 // 0..15
  const int bh = blockIdx.y;                 // 0..31
  const int b = bh >> 4, h = bh & 15;

  const size_t qkbase = ((size_t)b * 2048) * 1024 + h * 64;   // [B,S,H,dh]
  const size_t vtbase = ((size_t)(b * 16 + h) * 64) * 2048;   // [B,H,dh,S']
  const int qbase = qt * 128 + w * 32;

  bf16x8 qf[2][2];
#pragma unroll
  for (int t2 = 0; t2 < 2; ++t2)
#pragma unroll
    for (int ks = 0; ks < 2; ++ks)
      qf[t2][ks] = *(const bf16x8*)(Q + qkbase + (size_t)(qbase + t2 * 16 + c) * 1024 +
                                    ks * 32 + q4 * 8);

  float lpart[2] = {0.f, 0.f};
  f32x4 oacc[2][4];
#pragma unroll
  for (int t2 = 0; t2 < 2; ++t2)
#pragma unroll
    for (int dt = 0; dt < 4; ++dt) { f32x4 zv = {0.f, 0.f, 0.f, 0.f}; oacc[t2][dt] = zv; }

  int krow[4], klc[4], vrow[4], vlc[4];
#pragma unroll
  for (int i = 0; i < 4; ++i) {
    int ci = i * 256 + w * 64 + lane;
    krow[i] = ci >> 3; klc[i] = ((ci & 7) ^ (krow[i] & 7)) * 8;
    vrow[i] = ci >> 4; vlc[i] = ((ci & 15) ^ (vrow[i] & 15)) * 8;
  }

  for (int kt = 0; kt < 16; ++kt) {
    __syncthreads();
#pragma unroll
    for (int i = 0; i < 4; ++i) {
      gl_lds16(K + qkbase + (size_t)(kt * 128 + krow[i]) * 1024 + klc[i],
               Ks + (i * 256 + w * 64) * 8);
      gl_lds16(Vt + vtbase + (size_t)vrow[i] * 2048 + kt * 128 + vlc[i],
               Vs + (i * 256 + w * 64) * 8);
    }
    __syncthreads();

    f32x4 sacc[2][8];
#pragma unroll
    for (int t2 = 0; t2 < 2; ++t2)
#pragma unroll
      for (int a = 0; a < 8; ++a) { f32x4 iv = {-M0, -M0, -M0, -M0}; sacc[t2][a] = iv; }
#pragma unroll
    for (int ks = 0; ks < 2; ++ks) {
#pragma unroll
      for (int a = 0; a < 8; ++a) {
        bf16x8 kf = *(const bf16x8*)(Ks + (a * 16 + c) * 64 + (((ks * 4 + q4) ^ (c & 7)) * 8));
        sacc[0][a] = __builtin_amdgcn_mfma_f32_16x16x32_bf16(kf, qf[0][ks], sacc[0][a], 0, 0, 0);
        sacc[1][a] = __builtin_amdgcn_mfma_f32_16x16x32_bf16(kf, qf[1][ks], sacc[1][a], 0, 0, 0);
      }
    }

    u32 pk[2][8][2];
#pragma unroll
    for (int t2 = 0; t2 < 2; ++t2) {
      float rs = 0.f;
#pragma unroll
      for (int a = 0; a < 8; ++a) {
        FU p0, p1, p2, p3;
        p0.f = __builtin_amdgcn_exp2f(sacc[t2][a][0]);
        p1.f = __builtin_amdgcn_exp2f(sacc[t2][a][1]);
        p2.f = __builtin_amdgcn_exp2f(sacc[t2][a][2]);
        p3.f = __builtin_amdgcn_exp2f(sacc[t2][a][3]);
        FU t0, t1, t2u, t3;
        t0.u = p0.u & 0xFFFF0000u; t1.u = p1.u & 0xFFFF0000u;
        t2u.u = p2.u & 0xFFFF0000u; t3.u = p3.u & 0xFFFF0000u;
        rs += (t0.f + t1.f) + (t2u.f + t3.f);
        pk[t2][a][0] = __builtin_amdgcn_perm(p1.u, p0.u, 0x07060302u);
        pk[t2][a][1] = __builtin_amdgcn_perm(p3.u, p2.u, 0x07060302u);
      }
      lpart[t2] += rs;
    }

#pragma unroll
    for (int kch = 0; kch < 4; ++kch) {
      BF8 pf0, pf1;
      pf0.u[0] = pk[0][2 * kch][0];     pf0.u[1] = pk[0][2 * kch][1];
      pf0.u[2] = pk[0][2 * kch + 1][0]; pf0.u[3] = pk[0][2 * kch + 1][1];
      pf1.u[0] = pk[1][2 * kch][0];     pf1.u[1] = pk[1][2 * kch][1];
      pf1.u[2] = pk[1][2 * kch + 1][0]; pf1.u[3] = pk[1][2 * kch + 1][1];
#pragma unroll
      for (int dt = 0; dt < 4; ++dt) {
        bf16x8 vf = *(const bf16x8*)(Vs + (dt * 16 + c) * 128 + (((kch * 4 + q4) ^ c) * 8));
        oacc[0][dt] = __builtin_amdgcn_mfma_f32_16x16x32_bf16(vf, pf0.v, oacc[0][dt], 0, 0, 0);
        oacc[1][dt] = __builtin_amdgcn_mfma_f32_16x16x32_bf16(vf, pf1.v, oacc[1][dt], 0, 0, 0);
      }
    }
  }

#pragma unroll
  for (int t2 = 0; t2 < 2; ++t2) {
    float l = lpart[t2];
    l += __shfl_xor(l, 16, 64);
    l += __shfl_xor(l, 32, 64);
    float inv = 1.0f / l;
    size_t rowbase = qkbase + (size_t)(qbase + t2 * 16 + c) * 1024;
#pragma unroll
    for (int dt = 0; dt < 4; ++dt) {
      ushort4 o;
      o.x = f2bf(oacc[t2][dt][0] * inv);
      o.y = f2bf(oacc[t2][dt][1] * inv);
      o.z = f2bf(oacc[t2][dt][2] * inv);
      o.w = f2bf(oacc[t2][dt][3] * inv);
      *(ushort4*)(O + rowbase + dt * 16 + q4 * 4) = o;
    }
  }
}

// ---------- final projection: out = O @ Wo^T + bo (fp32 out), tile 128x64 ----------
__global__ void __launch_bounds__(256) out_gemm(const u16* __restrict__ A, const u16* __restrict__ W,
                                                const float* __restrict__ bias,
                                                float* __restrict__ Cout) {
  __shared__ u16 lds[2 * (128 + 64) * 64];   // 48 KiB
  f32x4 acc[4][2];
#pragma unroll
  for (int i = 0; i < 4; ++i)
#pragma unroll
    for (int j = 0; j < 2; ++j) { f32x4 zv = {0.f, 0.f, 0.f, 0.f}; acc[i][j] = zv; }

  const int m0 = blockIdx.y * 128, n0 = blockIdx.x * 64;
  gemm_pipe<128, 64>(A, W, lds, acc, m0, n0);

  const int tid = threadIdx.x, w = tid >> 6, lane = tid & 63;
  const int wm = (w >> 1) * 64, wn = (w & 1) * 32;
  const int q4 = lane >> 4, c = lane & 15;
#pragma unroll
  for (int j = 0; j < 2; ++j) {
    int n = n0 + wn + j * 16 + c;
    float bv = bias[n];
#pragma unroll
    for (int i = 0; i < 4; ++i)
#pragma unroll
      for (int r = 0; r < 4; ++r) {
        int m = m0 + wm + i * 16 + q4 * 4 + r;
        Cout[(size_t)m * 1024 + n] = acc[i][j][r] + bv;
      }
  }
}

// ---------- launch ----------
extern "C" void kernel_launch(void* const* d_in, const int* in_sizes, int n_in,
                              void* d_out, int out_size, void* d_ws, size_t ws_size,
                              hipStream_t stream) {
  const float* hs = (const float*)d_in[0];
  const float* Wq = (const float*)d_in[1];
  const float* Wk = (const float*)d_in[2];
  const float* Wv = (const float*)d_in[3];
  const float* Wo = (const float*)d_in[4];
  const float* bo = (const float*)d_in[5];
  float* out = (float*)d_out;

  u16* Hb   = (u16*)d_ws;            // 4096*1024
  u16* Wqkv = Hb + 4096 * 1024;      // [3072,1024]: Wq, Wk, Wv contiguous
  u16* Wob  = Wqkv + 3 * 1024 * 1024;
  u16* Qw   = Wob + 1024 * 1024;     // [B,S,H,dh], pre-scaled by QSCALE
  u16* Kw   = Qw + 4096 * 1024;      // [B,S,H,dh]
  u16* Vtw  = Kw + 4096 * 1024;      // [B,H,dh,S'] sigma-permuted
  u16* Ow   = Vtw + 4096 * 1024;     // [B,S,H,dh]

  cvt_f32_bf16<<<4096, 256, 0, stream>>>(hs, Hb, 4096 * 1024);
  cvt_w4<<<4096, 256, 0, stream>>>(Wq, Wk, Wv, Wo, Wqkv);   // Wob = Wqkv + 3M

  qkv_gemm<<<dim3(48, 32), 256, 0, stream>>>(Hb, Wqkv, Qw, Kw, Vtw);
  attn<<<dim3(16, 32), 256, 0, stream>>>(Qw, Kw, Vtw, Ow);
  out_gemm<<<dim3(16, 32), 256, 0, stream>>>(Ow, Wob, bo, out);
}

// Round 6
// 346.415 us; speedup vs baseline: 1.0102x; 1.0102x over previous
//
#include <hip/hip_runtime.h>
#include <stdint.h>

typedef unsigned short u16;
typedef unsigned int u32;
typedef __bf16 bf16x8 __attribute__((ext_vector_type(8)));
typedef float f32x4 __attribute__((ext_vector_type(4)));

#define QSCALE 0.1803368801111244f   // 64^-0.5 * log2(e): S comes out in log2 domain
#define M0 18.0f                     // fixed softmax "max" in log2 domain (true |s| <~ 12)

// ---------- helpers ----------
__device__ __forceinline__ u16 f2bf(float f) {
  union { float f; unsigned u; } v; v.f = f;
  return (u16)((v.u + 0x7FFFu + ((v.u >> 16) & 1u)) >> 16);
}

__device__ __forceinline__ void gl_lds16(const void* g, void* l) {
  typedef __attribute__((address_space(1))) void* gp_t;
  typedef __attribute__((address_space(3))) void* lp_t;
  __builtin_amdgcn_global_load_lds((gp_t)(g), (lp_t)(l), 16, 0, 0);
}

union BF8 { u32 u[4]; bf16x8 v; };
union FU { float f; u32 u; };

// ---------- fp32 -> bf16 converts ----------
__global__ void __launch_bounds__(256) cvt_f32_bf16(const float* __restrict__ in,
                                                    u16* __restrict__ out, int n) {
  int i = (blockIdx.x * 256 + threadIdx.x) * 4;
  if (i < n) {
    float4 f = *(const float4*)(in + i);
    ushort4 o;
    o.x = f2bf(f.x); o.y = f2bf(f.y); o.z = f2bf(f.z); o.w = f2bf(f.w);
    *(ushort4*)(out + i) = o;
  }
}

// 4 weight matrices (1M elements each) -> contiguous bf16 dst
__global__ void __launch_bounds__(256) cvt_w4(const float* __restrict__ a,
                                              const float* __restrict__ b,
                                              const float* __restrict__ c,
                                              const float* __restrict__ d,
                                              u16* __restrict__ out) {
  int i = (blockIdx.x * 256 + threadIdx.x) * 4;
  int sel = i >> 20;
  const float* src = (sel == 0) ? a : (sel == 1) ? b : (sel == 2) ? c : d;
  float4 f = *(const float4*)(src + (i & 1048575));
  ushort4 o;
  o.x = f2bf(f.x); o.y = f2bf(f.y); o.z = f2bf(f.z); o.w = f2bf(f.w);
  *(ushort4*)(out + i) = o;
}

// ---------- pipelined MT x NT GEMM core: C = A @ W^T, K=1024, BK=64 ----------
// Depth-1 register prefetch + double-buffered LDS, spill-proof: ONE named register
// set, explicit As0/Bs0/As1/Bs1 pointers, kt-loop manually unrolled by 2 so no
// buffer/register is ever indexed by a runtime value. Global loads stay in flight
// across s_barrier (only ds ops need lgkm drain); the vmcnt wait lands on the
// ds_write of the NEXT tile, one full compute phase after issue.
template <int MT, int NT>
__device__ __forceinline__ void gemm_pipe(const u16* __restrict__ A, const u16* __restrict__ W,
                                          u16* __restrict__ lds,   // 2*(MT+NT)*64 u16
                                          f32x4 (&acc)[MT / 32][NT / 32],
                                          int m0, int n0) {
  constexpr int AG = MT / 32, BG = NT / 32;
  constexpr int ASZ = MT * 64, BSZ = NT * 64;
  u16* const As0 = lds;
  u16* const Bs0 = lds + ASZ;
  u16* const As1 = lds + ASZ + BSZ;
  u16* const Bs1 = lds + 2 * ASZ + BSZ;
  const int tid = threadIdx.x, w = tid >> 6, lane = tid & 63;
  const int wm = (w >> 1) * (MT / 2), wn = (w & 1) * (NT / 2);
  const int q4 = lane >> 4, c = lane & 15;

  // staging: chunk g = qq*256 + tid -> row = g>>3, kchunk = g&7 (swizzled LDS slot)
  size_t aga[AG], bga[BG];
  int alo[AG], blo[BG];
#pragma unroll
  for (int qq = 0; qq < AG; ++qq) {
    int g = qq * 256 + tid, row = g >> 3, kc = g & 7;
    aga[qq] = (size_t)(m0 + row) * 1024 + kc * 8;
    alo[qq] = row * 64 + ((kc ^ (row & 7)) * 8);
  }
#pragma unroll
  for (int qq = 0; qq < BG; ++qq) {
    int g = qq * 256 + tid, row = g >> 3, kc = g & 7;
    bga[qq] = (size_t)(n0 + row) * 1024 + kc * 8;
    blo[qq] = row * 64 + ((kc ^ (row & 7)) * 8);
  }

  int4 ar[AG], br[BG];   // single prefetch register set (~24 VGPRs)

#define LOAD_T(k0)                                                   \
  {                                                                  \
    _Pragma("unroll") for (int qq = 0; qq < AG; ++qq)                \
        ar[qq] = *(const int4*)(A + aga[qq] + (k0));                 \
    _Pragma("unroll") for (int qq = 0; qq < BG; ++qq)                \
        br[qq] = *(const int4*)(W + bga[qq] + (k0));                 \
  }
#define WRITE_T(Ad, Bd)                                              \
  {                                                                  \
    _Pragma("unroll") for (int qq = 0; qq < AG; ++qq)                \
        *(int4*)((Ad) + alo[qq]) = ar[qq];                           \
    _Pragma("unroll") for (int qq = 0; qq < BG; ++qq)                \
        *(int4*)((Bd) + blo[qq]) = br[qq];                           \
  }
#define COMPUTE_T(Asrc, Bsrc)                                        \
  {                                                                  \
    _Pragma("unroll") for (int ks = 0; ks < 2; ++ks) {               \
      bf16x8 af[AG], bfr[BG];                                        \
      _Pragma("unroll") for (int i = 0; i < AG; ++i) {               \
        int row = wm + i * 16 + c;                                   \
        af[i] = *(const bf16x8*)((Asrc) + row * 64 +                 \
                                 (((ks * 4 + q4) ^ (row & 7)) * 8)); \
      }                                                              \
      _Pragma("unroll") for (int j = 0; j < BG; ++j) {               \
        int row = wn + j * 16 + c;                                   \
        bfr[j] = *(const bf16x8*)((Bsrc) + row * 64 +                \
                                  (((ks * 4 + q4) ^ (row & 7)) * 8));\
      }                                                              \
      _Pragma("unroll") for (int i = 0; i < AG; ++i)                 \
        _Pragma("unroll") for (int j = 0; j < BG; ++j)               \
          acc[i][j] = __builtin_amdgcn_mfma_f32_16x16x32_bf16(       \
              af[i], bfr[j], acc[i][j], 0, 0, 0);                    \
    }                                                                \
  }

  // prologue: tile0 -> LDS buf0; tile1 -> regs
  LOAD_T(0)
  WRITE_T(As0, Bs0)
  LOAD_T(64)
  __syncthreads();

#pragma unroll
  for (int kt = 0; kt < 16; kt += 2) {
    // regs hold tile kt+1; buf0 holds tile kt
    WRITE_T(As1, Bs1)                       // tile kt+1 -> buf1 (vmcnt waits here)
    if (kt + 2 < 16) LOAD_T((kt + 2) * 64)  // tile kt+2 -> regs (in flight thru barrier)
    COMPUTE_T(As0, Bs0)                     // tile kt
    __syncthreads();
    if (kt + 2 < 16) WRITE_T(As0, Bs0)      // tile kt+2 -> buf0
    if (kt + 3 < 16) LOAD_T((kt + 3) * 64)  // tile kt+3 -> regs
    COMPUTE_T(As1, Bs1)                     // tile kt+1
    __syncthreads();
  }
#undef LOAD_T
#undef WRITE_T
#undef COMPUTE_T
}

// ---------- fused QKV projection: one GEMM vs [Wq;Wk;Wv] (N=3072), tile 128x64 ----------
// n0>>10 selects output: 0 -> Q (pre-scaled), 1 -> K, 2 -> V^T sigma-permuted.
__global__ void __launch_bounds__(256) qkv_gemm(const u16* __restrict__ Hb,
                                                const u16* __restrict__ Wqkv,
                                                u16* __restrict__ Q, u16* __restrict__ K,
                                                u16* __restrict__ Vt) {
  __shared__ u16 lds[2 * (128 + 64) * 64];   // 48 KiB
  f32x4 acc[4][2];
#pragma unroll
  for (int i = 0; i < 4; ++i)
#pragma unroll
    for (int j = 0; j < 2; ++j) { f32x4 zv = {0.f, 0.f, 0.f, 0.f}; acc[i][j] = zv; }

  const int m0 = blockIdx.y * 128, n0g = blockIdx.x * 64;
  gemm_pipe<128, 64>(Hb, Wqkv, lds, acc, m0, n0g);

  const int z = n0g >> 10, nl0 = n0g & 1023;
  const int tid = threadIdx.x, w = tid >> 6, lane = tid & 63;
  const int wm = (w >> 1) * 64, wn = (w & 1) * 32;
  const int q4 = lane >> 4, c = lane & 15;

#pragma unroll
  for (int i = 0; i < 4; ++i)
#pragma unroll
    for (int j = 0; j < 2; ++j)
#pragma unroll
      for (int r = 0; r < 4; ++r) {
        int m = m0 + wm + i * 16 + q4 * 4 + r;       // b*2048 + s
        int n = nl0 + wn + j * 16 + c;               // h*64 + d (within 1024)
        if (z == 0) {
          Q[(size_t)m * 1024 + n] = f2bf(acc[i][j][r] * QSCALE);
        } else if (z == 1) {
          K[(size_t)m * 1024 + n] = f2bf(acc[i][j][r]);
        } else {
          int b = m >> 11, s = m & 2047, h = n >> 6, d = n & 63;
          int kv = s & 127;
          int sig = ((kv >> 5) << 5) | (((kv >> 2) & 3) << 3) | (((kv >> 4) & 1) << 2) | (kv & 3);
          int sp = (s & ~127) | sig;
          Vt[(((size_t)(b * 16 + h) * 64 + d) << 11) + sp] = f2bf(acc[i][j][r]);
        }
      }
}

// ---------- flash attention, S^T orientation, fixed-max streaming softmax ----------
// (unchanged from round 4)
__global__ void __launch_bounds__(256, 2) attn(const u16* __restrict__ Q, const u16* __restrict__ K,
                                               const u16* __restrict__ Vt, u16* __restrict__ O) {
  __shared__ u16 Ks[128 * 64];   // [kv 128][d 64], swizzled (8 chunks/row)
  __shared__ u16 Vs[64 * 128];   // [d 64][kv' 128], swizzled (16 chunks/row)

  const int tid = threadIdx.x, w = tid >> 6, lane = tid & 63;
  const int q4 = lane >> 4, c = lane & 15;
  const int qt = blockIdx.x;                 // 0..15
  const int bh = blockIdx.y;                 // 0..31
  const int b = bh >> 4, h = bh & 15;

  const size_t qkbase = ((size_t)b * 2048) * 1024 + h * 64;   // [B,S,H,dh]
  const size_t vtbase = ((size_t)(b * 16 + h) * 64) * 2048;   // [B,H,dh,S']
  const int qbase = qt * 128 + w * 32;

  bf16x8 qf[2][2];
#pragma unroll
  for (int t2 = 0; t2 < 2; ++t2)
#pragma unroll
    for (int ks = 0; ks < 2; ++ks)
      qf[t2][ks] = *(const bf16x8*)(Q + qkbase + (size_t)(qbase + t2 * 16 + c) * 1024 +
                                    ks * 32 + q4 * 8);

  float lpart[2] = {0.f, 0.f};
  f32x4 oacc[2][4];
#pragma unroll
  for (int t2 = 0; t2 < 2; ++t2)
#pragma unroll
    for (int dt = 0; dt < 4; ++dt) { f32x4 zv = {0.f, 0.f, 0.f, 0.f}; oacc[t2][dt] = zv; }

  int krow[4], klc[4], vrow[4], vlc[4];
#pragma unroll
  for (int i = 0; i < 4; ++i) {
    int ci = i * 256 + w * 64 + lane;
    krow[i] = ci >> 3; klc[i] = ((ci & 7) ^ (krow[i] & 7)) * 8;
    vrow[i] = ci >> 4; vlc[i] = ((ci & 15) ^ (vrow[i] & 15)) * 8;
  }

  for (int kt = 0; kt < 16; ++kt) {
    __syncthreads();
#pragma unroll
    for (int i = 0; i < 4; ++i) {
      gl_lds16(K + qkbase + (size_t)(kt * 128 + krow[i]) * 1024 + klc[i],
               Ks + (i * 256 + w * 64) * 8);
      gl_lds16(Vt + vtbase + (size_t)vrow[i] * 2048 + kt * 128 + vlc[i],
               Vs + (i * 256 + w * 64) * 8);
    }
    __syncthreads();

    f32x4 sacc[2][8];
#pragma unroll
    for (int t2 = 0; t2 < 2; ++t2)
#pragma unroll
      for (int a = 0; a < 8; ++a) { f32x4 iv = {-M0, -M0, -M0, -M0}; sacc[t2][a] = iv; }
#pragma unroll
    for (int ks = 0; ks < 2; ++ks) {
#pragma unroll
      for (int a = 0; a < 8; ++a) {
        bf16x8 kf = *(const bf16x8*)(Ks + (a * 16 + c) * 64 + (((ks * 4 + q4) ^ (c & 7)) * 8));
        sacc[0][a] = __builtin_amdgcn_mfma_f32_16x16x32_bf16(kf, qf[0][ks], sacc[0][a], 0, 0, 0);
        sacc[1][a] = __builtin_amdgcn_mfma_f32_16x16x32_bf16(kf, qf[1][ks], sacc[1][a], 0, 0, 0);
      }
    }

    u32 pk[2][8][2];
#pragma unroll
    for (int t2 = 0; t2 < 2; ++t2) {
      float rs = 0.f;
#pragma unroll
      for (int a = 0; a < 8; ++a) {
        FU p0, p1, p2, p3;
        p0.f = __builtin_amdgcn_exp2f(sacc[t2][a][0]);
        p1.f = __builtin_amdgcn_exp2f(sacc[t2][a][1]);
        p2.f = __builtin_amdgcn_exp2f(sacc[t2][a][2]);
        p3.f = __builtin_amdgcn_exp2f(sacc[t2][a][3]);
        FU t0, t1, t2u, t3;
        t0.u = p0.u & 0xFFFF0000u; t1.u = p1.u & 0xFFFF0000u;
        t2u.u = p2.u & 0xFFFF0000u; t3.u = p3.u & 0xFFFF0000u;
        rs += (t0.f + t1.f) + (t2u.f + t3.f);
        pk[t2][a][0] = __builtin_amdgcn_perm(p1.u, p0.u, 0x07060302u);
        pk[t2][a][1] = __builtin_amdgcn_perm(p3.u, p2.u, 0x07060302u);
      }
      lpart[t2] += rs;
    }

#pragma unroll
    for (int kch = 0; kch < 4; ++kch) {
      BF8 pf0, pf1;
      pf0.u[0] = pk[0][2 * kch][0];     pf0.u[1] = pk[0][2 * kch][1];
      pf0.u[2] = pk[0][2 * kch + 1][0]; pf0.u[3] = pk[0][2 * kch + 1][1];
      pf1.u[0] = pk[1][2 * kch][0];     pf1.u[1] = pk[1][2 * kch][1];
      pf1.u[2] = pk[1][2 * kch + 1][0]; pf1.u[3] = pk[1][2 * kch + 1][1];
#pragma unroll
      for (int dt = 0; dt < 4; ++dt) {
        bf16x8 vf = *(const bf16x8*)(Vs + (dt * 16 + c) * 128 + (((kch * 4 + q4) ^ c) * 8));
        oacc[0][dt] = __builtin_amdgcn_mfma_f32_16x16x32_bf16(vf, pf0.v, oacc[0][dt], 0, 0, 0);
        oacc[1][dt] = __builtin_amdgcn_mfma_f32_16x16x32_bf16(vf, pf1.v, oacc[1][dt], 0, 0, 0);
      }
    }
  }

#pragma unroll
  for (int t2 = 0; t2 < 2; ++t2) {
    float l = lpart[t2];
    l += __shfl_xor(l, 16, 64);
    l += __shfl_xor(l, 32, 64);
    float inv = 1.0f / l;
    size_t rowbase = qkbase + (size_t)(qbase + t2 * 16 + c) * 1024;
#pragma unroll
    for (int dt = 0; dt < 4; ++dt) {
      ushort4 o;
      o.x = f2bf(oacc[t2][dt][0] * inv);
      o.y = f2bf(oacc[t2][dt][1] * inv);
      o.z = f2bf(oacc[t2][dt][2] * inv);
      o.w = f2bf(oacc[t2][dt][3] * inv);
      *(ushort4*)(O + rowbase + dt * 16 + q4 * 4) = o;
    }
  }
}

// ---------- final projection: out = O @ Wo^T + bo (fp32 out), tile 128x64 ----------
__global__ void __launch_bounds__(256) out_gemm(const u16* __restrict__ A, const u16* __restrict__ W,
                                                const float* __restrict__ bias,
                                                float* __restrict__ Cout) {
  __shared__ u16 lds[2 * (128 + 64) * 64];   // 48 KiB
  f32x4 acc[4][2];
#pragma unroll
  for (int i = 0; i < 4; ++i)
#pragma unroll
    for (int j = 0; j < 2; ++j) { f32x4 zv = {0.f, 0.f, 0.f, 0.f}; acc[i][j] = zv; }

  const int m0 = blockIdx.y * 128, n0 = blockIdx.x * 64;
  gemm_pipe<128, 64>(A, W, lds, acc, m0, n0);

  const int tid = threadIdx.x, w = tid >> 6, lane = tid & 63;
  const int wm = (w >> 1) * 64, wn = (w & 1) * 32;
  const int q4 = lane >> 4, c = lane & 15;
#pragma unroll
  for (int j = 0; j < 2; ++j) {
    int n = n0 + wn + j * 16 + c;
    float bv = bias[n];
#pragma unroll
    for (int i = 0; i < 4; ++i)
#pragma unroll
      for (int r = 0; r < 4; ++r) {
        int m = m0 + wm + i * 16 + q4 * 4 + r;
        Cout[(size_t)m * 1024 + n] = acc[i][j][r] + bv;
      }
  }
}

// ---------- launch ----------
extern "C" void kernel_launch(void* const* d_in, const int* in_sizes, int n_in,
                              void* d_out, int out_size, void* d_ws, size_t ws_size,
                              hipStream_t stream) {
  const float* hs = (const float*)d_in[0];
  const float* Wq = (const float*)d_in[1];
  const float* Wk = (const float*)d_in[2];
  const float* Wv = (const float*)d_in[3];
  const float* Wo = (const float*)d_in[4];
  const float* bo = (const float*)d_in[5];
  float* out = (float*)d_out;

  u16* Hb   = (u16*)d_ws;            // 4096*1024
  u16* Wqkv = Hb + 4096 * 1024;      // [3072,1024]: Wq, Wk, Wv contiguous
  u16* Wob  = Wqkv + 3 * 1024 * 1024;
  u16* Qw   = Wob + 1024 * 1024;     // [B,S,H,dh], pre-scaled by QSCALE
  u16* Kw   = Qw + 4096 * 1024;      // [B,S,H,dh]
  u16* Vtw  = Kw + 4096 * 1024;      // [B,H,dh,S'] sigma-permuted
  u16* Ow   = Vtw + 4096 * 1024;     // [B,S,H,dh]

  cvt_f32_bf16<<<4096, 256, 0, stream>>>(hs, Hb, 4096 * 1024);
  cvt_w4<<<4096, 256, 0, stream>>>(Wq, Wk, Wv, Wo, Wqkv);   // Wob = Wqkv + 3M

  qkv_gemm<<<dim3(48, 32), 256, 0, stream>>>(Hb, Wqkv, Qw, Kw, Vtw);
  attn<<<dim3(16, 32), 256, 0, stream>>>(Qw, Kw, Vtw, Ow);
  out_gemm<<<dim3(16, 32), 256, 0, stream>>>(Ow, Wob, bo, out);
}

// Round 7
// 220.341 us; speedup vs baseline: 1.5882x; 1.5722x over previous
//
#include <hip/hip_runtime.h>
#include <stdint.h>

typedef unsigned short u16;
typedef unsigned int u32;
typedef __bf16 bf16x8 __attribute__((ext_vector_type(8)));
typedef float f32x4 __attribute__((ext_vector_type(4)));

#define QSCALE 0.1803368801111244f   // 64^-0.5 * log2(e): S comes out in log2 domain
#define M0 18.0f                     // fixed softmax "max" in log2 domain (true |s| <~ 12)

// ---------- helpers ----------
__device__ __forceinline__ u16 f2bf(float f) {
  union { float f; unsigned u; } v; v.f = f;
  return (u16)((v.u + 0x7FFFu + ((v.u >> 16) & 1u)) >> 16);
}

__device__ __forceinline__ void gl_lds16(const void* g, void* l) {
  typedef __attribute__((address_space(1))) void* gp_t;
  typedef __attribute__((address_space(3))) void* lp_t;
  __builtin_amdgcn_global_load_lds((gp_t)(g), (lp_t)(l), 16, 0, 0);
}

union BF8 { u32 u[4]; bf16x8 v; };
union FU { float f; u32 u; };

// ---------- fp32 -> bf16 converts ----------
__global__ void __launch_bounds__(256) cvt_f32_bf16(const float* __restrict__ in,
                                                    u16* __restrict__ out, int n) {
  int i = (blockIdx.x * 256 + threadIdx.x) * 4;
  if (i < n) {
    float4 f = *(const float4*)(in + i);
    ushort4 o;
    o.x = f2bf(f.x); o.y = f2bf(f.y); o.z = f2bf(f.z); o.w = f2bf(f.w);
    *(ushort4*)(out + i) = o;
  }
}

// 4 weight matrices (1M elements each) -> contiguous bf16 dst
__global__ void __launch_bounds__(256) cvt_w4(const float* __restrict__ a,
                                              const float* __restrict__ b,
                                              const float* __restrict__ c,
                                              const float* __restrict__ d,
                                              u16* __restrict__ out) {
  int i = (blockIdx.x * 256 + threadIdx.x) * 4;
  int sel = i >> 20;
  const float* src = (sel == 0) ? a : (sel == 1) ? b : (sel == 2) ? c : d;
  float4 f = *(const float4*)(src + (i & 1048575));
  ushort4 o;
  o.x = f2bf(f.x); o.y = f2bf(f.y); o.z = f2bf(f.z); o.w = f2bf(f.w);
  *(ushort4*)(out + i) = o;
}

// ---------- m97-style MT x NT GEMM core: C = A @ W^T, K=1024, BK=64 ----------
// global_load_lds width-16 staging, single-buffered LDS, 2-barrier K-loop.
// 256 threads = 4 waves in 2x2. XOR-swizzled LDS (slot s in row r holds chunk s^(r&7)).
template <int MT, int NT>
__device__ __forceinline__ void gemm_core_t(const u16* __restrict__ A, const u16* __restrict__ W,
                                            u16* As, u16* Bs,
                                            f32x4 (&acc)[MT / 32][NT / 32],
                                            int m0, int n0) {
  constexpr int AG = MT / 32, BG = NT / 32;   // staging groups AND frag count per wave
  const int tid  = threadIdx.x;
  const int w    = tid >> 6, lane = tid & 63;
  const int wm   = (w >> 1) * (MT / 2), wn = (w & 1) * (NT / 2);
  const int srow = lane >> 3;
  const int slc  = ((lane & 7) ^ (srow & 7)) * 8;
  const int q4   = lane >> 4, c = lane & 15;

  for (int k0 = 0; k0 < 1024; k0 += 64) {
#pragma unroll
    for (int qq = 0; qq < AG; ++qq) {
      int chunk = w * AG + qq;
      gl_lds16(A + (size_t)(m0 + chunk * 8 + srow) * 1024 + k0 + slc, As + chunk * 512);
    }
#pragma unroll
    for (int qq = 0; qq < BG; ++qq) {
      int chunk = w * BG + qq;
      gl_lds16(W + (size_t)(n0 + chunk * 8 + srow) * 1024 + k0 + slc, Bs + chunk * 512);
    }
    __syncthreads();
#pragma unroll
    for (int ks = 0; ks < 2; ++ks) {
      bf16x8 af[AG], bfr[BG];
#pragma unroll
      for (int i = 0; i < AG; ++i) {
        int row = wm + i * 16 + c;
        af[i] = *(const bf16x8*)(As + row * 64 + (((ks * 4 + q4) ^ (row & 7)) * 8));
      }
#pragma unroll
      for (int j = 0; j < BG; ++j) {
        int row = wn + j * 16 + c;
        bfr[j] = *(const bf16x8*)(Bs + row * 64 + (((ks * 4 + q4) ^ (row & 7)) * 8));
      }
#pragma unroll
      for (int i = 0; i < AG; ++i)
#pragma unroll
        for (int j = 0; j < BG; ++j)
          acc[i][j] = __builtin_amdgcn_mfma_f32_16x16x32_bf16(af[i], bfr[j], acc[i][j], 0, 0, 0);
    }
    __syncthreads();
  }
}

// ---------- fused QKV projection: one GEMM vs [Wq;Wk;Wv] (N=3072), tile 128x128 ----------
// n0>>10 selects output: 0 -> Q (pre-scaled), 1 -> K, 2 -> V^T sigma-permuted.
__global__ void __launch_bounds__(256, 3) qkv_gemm(const u16* __restrict__ Hb,
                                                   const u16* __restrict__ Wqkv,
                                                   u16* __restrict__ Q, u16* __restrict__ K,
                                                   u16* __restrict__ Vt) {
  __shared__ u16 As[128 * 64];
  __shared__ u16 Bs[128 * 64];
  f32x4 acc[4][4];
#pragma unroll
  for (int i = 0; i < 4; ++i)
#pragma unroll
    for (int j = 0; j < 4; ++j) { f32x4 zv = {0.f, 0.f, 0.f, 0.f}; acc[i][j] = zv; }

  const int m0 = blockIdx.y * 128, n0g = blockIdx.x * 128;
  gemm_core_t<128, 128>(Hb, Wqkv, As, Bs, acc, m0, n0g);

  const int z = n0g >> 10, nl0 = n0g & 1023;
  const int tid = threadIdx.x, w = tid >> 6, lane = tid & 63;
  const int wm = (w >> 1) * 64, wn = (w & 1) * 64;
  const int q4 = lane >> 4, c = lane & 15;

#pragma unroll
  for (int i = 0; i < 4; ++i)
#pragma unroll
    for (int j = 0; j < 4; ++j)
#pragma unroll
      for (int r = 0; r < 4; ++r) {
        int m = m0 + wm + i * 16 + q4 * 4 + r;       // b*2048 + s
        int n = nl0 + wn + j * 16 + c;               // h*64 + d (within 1024)
        if (z == 0) {
          Q[(size_t)m * 1024 + n] = f2bf(acc[i][j][r] * QSCALE);
        } else if (z == 1) {
          K[(size_t)m * 1024 + n] = f2bf(acc[i][j][r]);
        } else {
          int b = m >> 11, s = m & 2047, h = n >> 6, d = n & 63;
          int kv = s & 127;
          int sig = ((kv >> 5) << 5) | (((kv >> 2) & 3) << 3) | (((kv >> 4) & 1) << 2) | (kv & 3);
          int sp = (s & ~127) | sig;
          Vt[(((size_t)(b * 16 + h) * 64 + d) << 11) + sp] = f2bf(acc[i][j][r]);
        }
      }
}

// ---------- flash attention, S^T orientation, fixed-max streaming softmax ----------
__global__ void __launch_bounds__(256, 3) attn(const u16* __restrict__ Q, const u16* __restrict__ K,
                                               const u16* __restrict__ Vt, u16* __restrict__ O) {
  __shared__ u16 Ks[128 * 64];   // [kv 128][d 64], swizzled (8 chunks/row)
  __shared__ u16 Vs[64 * 128];   // [d 64][kv' 128], swizzled (16 chunks/row)

  const int tid = threadIdx.x, w = tid >> 6, lane = tid & 63;
  const int q4 = lane >> 4, c = lane & 15;
  const int qt = blockIdx.x;                 // 0..15
  const int bh = blockIdx.y;                 // 0..31
  const int b = bh >> 4, h = bh & 15;

  const size_t qkbase = ((size_t)b * 2048) * 1024 + h * 64;   // [B,S,H,dh]
  const size_t vtbase = ((size_t)(b * 16 + h) * 64) * 2048;   // [B,H,dh,S']
  const int qbase = qt * 128 + w * 32;

  bf16x8 qf[2][2];
#pragma unroll
  for (int t2 = 0; t2 < 2; ++t2)
#pragma unroll
    for (int ks = 0; ks < 2; ++ks)
      qf[t2][ks] = *(const bf16x8*)(Q + qkbase + (size_t)(qbase + t2 * 16 + c) * 1024 +
                                    ks * 32 + q4 * 8);

  float lpart[2] = {0.f, 0.f};
  f32x4 oacc[2][4];
#pragma unroll
  for (int t2 = 0; t2 < 2; ++t2)
#pragma unroll
    for (int dt = 0; dt < 4; ++dt) { f32x4 zv = {0.f, 0.f, 0.f, 0.f}; oacc[t2][dt] = zv; }

  int krow[4], klc[4], vrow[4], vlc[4];
#pragma unroll
  for (int i = 0; i < 4; ++i) {
    int ci = i * 256 + w * 64 + lane;
    krow[i] = ci >> 3; klc[i] = ((ci & 7) ^ (krow[i] & 7)) * 8;
    vrow[i] = ci >> 4; vlc[i] = ((ci & 15) ^ (vrow[i] & 15)) * 8;
  }

  for (int kt = 0; kt < 16; ++kt) {
    __syncthreads();
#pragma unroll
    for (int i = 0; i < 4; ++i) {
      gl_lds16(K + qkbase + (size_t)(kt * 128 + krow[i]) * 1024 + klc[i],
               Ks + (i * 256 + w * 64) * 8);
      gl_lds16(Vt + vtbase + (size_t)vrow[i] * 2048 + kt * 128 + vlc[i],
               Vs + (i * 256 + w * 64) * 8);
    }
    __syncthreads();

    f32x4 sacc[2][8];
#pragma unroll
    for (int t2 = 0; t2 < 2; ++t2)
#pragma unroll
      for (int a = 0; a < 8; ++a) { f32x4 iv = {-M0, -M0, -M0, -M0}; sacc[t2][a] = iv; }
#pragma unroll
    for (int ks = 0; ks < 2; ++ks) {
#pragma unroll
      for (int a = 0; a < 8; ++a) {
        bf16x8 kf = *(const bf16x8*)(Ks + (a * 16 + c) * 64 + (((ks * 4 + q4) ^ (c & 7)) * 8));
        sacc[0][a] = __builtin_amdgcn_mfma_f32_16x16x32_bf16(kf, qf[0][ks], sacc[0][a], 0, 0, 0);
        sacc[1][a] = __builtin_amdgcn_mfma_f32_16x16x32_bf16(kf, qf[1][ks], sacc[1][a], 0, 0, 0);
      }
    }

    u32 pk[2][8][2];
#pragma unroll
    for (int t2 = 0; t2 < 2; ++t2) {
      float rs = 0.f;
#pragma unroll
      for (int a = 0; a < 8; ++a) {
        FU p0, p1, p2, p3;
        p0.f = __builtin_amdgcn_exp2f(sacc[t2][a][0]);
        p1.f = __builtin_amdgcn_exp2f(sacc[t2][a][1]);
        p2.f = __builtin_amdgcn_exp2f(sacc[t2][a][2]);
        p3.f = __builtin_amdgcn_exp2f(sacc[t2][a][3]);
        FU t0, t1, t2u, t3;
        t0.u = p0.u & 0xFFFF0000u; t1.u = p1.u & 0xFFFF0000u;
        t2u.u = p2.u & 0xFFFF0000u; t3.u = p3.u & 0xFFFF0000u;
        rs += (t0.f + t1.f) + (t2u.f + t3.f);
        pk[t2][a][0] = __builtin_amdgcn_perm(p1.u, p0.u, 0x07060302u);
        pk[t2][a][1] = __builtin_amdgcn_perm(p3.u, p2.u, 0x07060302u);
      }
      lpart[t2] += rs;
    }

#pragma unroll
    for (int kch = 0; kch < 4; ++kch) {
      BF8 pf0, pf1;
      pf0.u[0] = pk[0][2 * kch][0];     pf0.u[1] = pk[0][2 * kch][1];
      pf0.u[2] = pk[0][2 * kch + 1][0]; pf0.u[3] = pk[0][2 * kch + 1][1];
      pf1.u[0] = pk[1][2 * kch][0];     pf1.u[1] = pk[1][2 * kch][1];
      pf1.u[2] = pk[1][2 * kch + 1][0]; pf1.u[3] = pk[1][2 * kch + 1][1];
#pragma unroll
      for (int dt = 0; dt < 4; ++dt) {
        bf16x8 vf = *(const bf16x8*)(Vs + (dt * 16 + c) * 128 + (((kch * 4 + q4) ^ c) * 8));
        oacc[0][dt] = __builtin_amdgcn_mfma_f32_16x16x32_bf16(vf, pf0.v, oacc[0][dt], 0, 0, 0);
        oacc[1][dt] = __builtin_amdgcn_mfma_f32_16x16x32_bf16(vf, pf1.v, oacc[1][dt], 0, 0, 0);
      }
    }
  }

#pragma unroll
  for (int t2 = 0; t2 < 2; ++t2) {
    float l = lpart[t2];
    l += __shfl_xor(l, 16, 64);
    l += __shfl_xor(l, 32, 64);
    float inv = 1.0f / l;
    size_t rowbase = qkbase + (size_t)(qbase + t2 * 16 + c) * 1024;
#pragma unroll
    for (int dt = 0; dt < 4; ++dt) {
      ushort4 o;
      o.x = f2bf(oacc[t2][dt][0] * inv);
      o.y = f2bf(oacc[t2][dt][1] * inv);
      o.z = f2bf(oacc[t2][dt][2] * inv);
      o.w = f2bf(oacc[t2][dt][3] * inv);
      *(ushort4*)(O + rowbase + dt * 16 + q4 * 4) = o;
    }
  }
}

// ---------- final projection: out = O @ Wo^T + bo (fp32 out), tile 128x64 ----------
__global__ void __launch_bounds__(256) out_gemm(const u16* __restrict__ A, const u16* __restrict__ W,
                                                const float* __restrict__ bias,
                                                float* __restrict__ Cout) {
  __shared__ u16 As[128 * 64];
  __shared__ u16 Bs[64 * 64];
  f32x4 acc[4][2];
#pragma unroll
  for (int i = 0; i < 4; ++i)
#pragma unroll
    for (int j = 0; j < 2; ++j) { f32x4 zv = {0.f, 0.f, 0.f, 0.f}; acc[i][j] = zv; }

  const int m0 = blockIdx.y * 128, n0 = blockIdx.x * 64;
  gemm_core_t<128, 64>(A, W, As, Bs, acc, m0, n0);

  const int tid = threadIdx.x, w = tid >> 6, lane = tid & 63;
  const int wm = (w >> 1) * 64, wn = (w & 1) * 32;
  const int q4 = lane >> 4, c = lane & 15;
#pragma unroll
  for (int j = 0; j < 2; ++j) {
    int n = n0 + wn + j * 16 + c;
    float bv = bias[n];
#pragma unroll
    for (int i = 0; i < 4; ++i)
#pragma unroll
      for (int r = 0; r < 4; ++r) {
        int m = m0 + wm + i * 16 + q4 * 4 + r;
        Cout[(size_t)m * 1024 + n] = acc[i][j][r] + bv;
      }
  }
}

// ---------- launch ----------
extern "C" void kernel_launch(void* const* d_in, const int* in_sizes, int n_in,
                              void* d_out, int out_size, void* d_ws, size_t ws_size,
                              hipStream_t stream) {
  const float* hs = (const float*)d_in[0];
  const float* Wq = (const float*)d_in[1];
  const float* Wk = (const float*)d_in[2];
  const float* Wv = (const float*)d_in[3];
  const float* Wo = (const float*)d_in[4];
  const float* bo = (const float*)d_in[5];
  float* out = (float*)d_out;

  u16* Hb   = (u16*)d_ws;            // 4096*1024
  u16* Wqkv = Hb + 4096 * 1024;      // [3072,1024]: Wq, Wk, Wv contiguous
  u16* Wob  = Wqkv + 3 * 1024 * 1024;
  u16* Qw   = Wob + 1024 * 1024;     // [B,S,H,dh], pre-scaled by QSCALE
  u16* Kw   = Qw + 4096 * 1024;      // [B,S,H,dh]
  u16* Vtw  = Kw + 4096 * 1024;      // [B,H,dh,S'] sigma-permuted
  u16* Ow   = Vtw + 4096 * 1024;     // [B,S,H,dh]

  cvt_f32_bf16<<<4096, 256, 0, stream>>>(hs, Hb, 4096 * 1024);
  cvt_w4<<<4096, 256, 0, stream>>>(Wq, Wk, Wv, Wo, Wqkv);   // Wob = Wqkv + 3M

  qkv_gemm<<<dim3(24, 32), 256, 0, stream>>>(Hb, Wqkv, Qw, Kw, Vtw);
  attn<<<dim3(16, 32), 256, 0, stream>>>(Qw, Kw, Vtw, Ow);
  out_gemm<<<dim3(16, 32), 256, 0, stream>>>(Ow, Wob, bo, out);
}

// Round 8
// 213.947 us; speedup vs baseline: 1.6357x; 1.0299x over previous
//
#include <hip/hip_runtime.h>
#include <stdint.h>

typedef unsigned short u16;
typedef unsigned int u32;
typedef __bf16 bf16x8 __attribute__((ext_vector_type(8)));
typedef float f32x4 __attribute__((ext_vector_type(4)));

#define QSCALE 0.1803368801111244f   // 64^-0.5 * log2(e): S comes out in log2 domain
#define M0 18.0f                     // fixed softmax "max" in log2 domain (true |s| <~ 12)

// ---------- helpers ----------
__device__ __forceinline__ u16 f2bf(float f) {
  union { float f; unsigned u; } v; v.f = f;
  return (u16)((v.u + 0x7FFFu + ((v.u >> 16) & 1u)) >> 16);
}

__device__ __forceinline__ void gl_lds16(const void* g, void* l) {
  typedef __attribute__((address_space(1))) void* gp_t;
  typedef __attribute__((address_space(3))) void* lp_t;
  __builtin_amdgcn_global_load_lds((gp_t)(g), (lp_t)(l), 16, 0, 0);
}

union BF8 { u32 u[4]; bf16x8 v; };
union FU { float f; u32 u; };

// ---------- fp32 -> bf16 converts ----------
__global__ void __launch_bounds__(256) cvt_f32_bf16(const float* __restrict__ in,
                                                    u16* __restrict__ out, int n) {
  int i = (blockIdx.x * 256 + threadIdx.x) * 4;
  if (i < n) {
    float4 f = *(const float4*)(in + i);
    ushort4 o;
    o.x = f2bf(f.x); o.y = f2bf(f.y); o.z = f2bf(f.z); o.w = f2bf(f.w);
    *(ushort4*)(out + i) = o;
  }
}

// 4 weight matrices (1M elements each) -> contiguous bf16 dst
__global__ void __launch_bounds__(256) cvt_w4(const float* __restrict__ a,
                                              const float* __restrict__ b,
                                              const float* __restrict__ c,
                                              const float* __restrict__ d,
                                              u16* __restrict__ out) {
  int i = (blockIdx.x * 256 + threadIdx.x) * 4;
  int sel = i >> 20;
  const float* src = (sel == 0) ? a : (sel == 1) ? b : (sel == 2) ? c : d;
  float4 f = *(const float4*)(src + (i & 1048575));
  ushort4 o;
  o.x = f2bf(f.x); o.y = f2bf(f.y); o.z = f2bf(f.z); o.w = f2bf(f.w);
  *(ushort4*)(out + i) = o;
}

// ---------- m97-style MT x NT GEMM core: C = A @ W^T, K=1024, BK=64 ----------
template <int MT, int NT>
__device__ __forceinline__ void gemm_core_t(const u16* __restrict__ A, const u16* __restrict__ W,
                                            u16* As, u16* Bs,
                                            f32x4 (&acc)[MT / 32][NT / 32],
                                            int m0, int n0) {
  constexpr int AG = MT / 32, BG = NT / 32;
  const int tid  = threadIdx.x;
  const int w    = tid >> 6, lane = tid & 63;
  const int wm   = (w >> 1) * (MT / 2), wn = (w & 1) * (NT / 2);
  const int srow = lane >> 3;
  const int slc  = ((lane & 7) ^ (srow & 7)) * 8;
  const int q4   = lane >> 4, c = lane & 15;

  for (int k0 = 0; k0 < 1024; k0 += 64) {
#pragma unroll
    for (int qq = 0; qq < AG; ++qq) {
      int chunk = w * AG + qq;
      gl_lds16(A + (size_t)(m0 + chunk * 8 + srow) * 1024 + k0 + slc, As + chunk * 512);
    }
#pragma unroll
    for (int qq = 0; qq < BG; ++qq) {
      int chunk = w * BG + qq;
      gl_lds16(W + (size_t)(n0 + chunk * 8 + srow) * 1024 + k0 + slc, Bs + chunk * 512);
    }
    __syncthreads();
#pragma unroll
    for (int ks = 0; ks < 2; ++ks) {
      bf16x8 af[AG], bfr[BG];
#pragma unroll
      for (int i = 0; i < AG; ++i) {
        int row = wm + i * 16 + c;
        af[i] = *(const bf16x8*)(As + row * 64 + (((ks * 4 + q4) ^ (row & 7)) * 8));
      }
#pragma unroll
      for (int j = 0; j < BG; ++j) {
        int row = wn + j * 16 + c;
        bfr[j] = *(const bf16x8*)(Bs + row * 64 + (((ks * 4 + q4) ^ (row & 7)) * 8));
      }
#pragma unroll
      for (int i = 0; i < AG; ++i)
#pragma unroll
        for (int j = 0; j < BG; ++j)
          acc[i][j] = __builtin_amdgcn_mfma_f32_16x16x32_bf16(af[i], bfr[j], acc[i][j], 0, 0, 0);
    }
    __syncthreads();
  }
}

// ---------- fused QKV projection: one GEMM vs [Wq;Wk;Wv] (N=3072), tile 128x128 ----------
__global__ void __launch_bounds__(256) qkv_gemm(const u16* __restrict__ Hb,
                                                const u16* __restrict__ Wqkv,
                                                u16* __restrict__ Q, u16* __restrict__ K,
                                                u16* __restrict__ Vt) {
  __shared__ u16 As[128 * 64];
  __shared__ u16 Bs[128 * 64];
  f32x4 acc[4][4];
#pragma unroll
  for (int i = 0; i < 4; ++i)
#pragma unroll
    for (int j = 0; j < 4; ++j) { f32x4 zv = {0.f, 0.f, 0.f, 0.f}; acc[i][j] = zv; }

  const int m0 = blockIdx.y * 128, n0g = blockIdx.x * 128;
  gemm_core_t<128, 128>(Hb, Wqkv, As, Bs, acc, m0, n0g);

  const int z = n0g >> 10, nl0 = n0g & 1023;
  const int tid = threadIdx.x, w = tid >> 6, lane = tid & 63;
  const int wm = (w >> 1) * 64, wn = (w & 1) * 64;
  const int q4 = lane >> 4, c = lane & 15;

#pragma unroll
  for (int i = 0; i < 4; ++i)
#pragma unroll
    for (int j = 0; j < 4; ++j)
#pragma unroll
      for (int r = 0; r < 4; ++r) {
        int m = m0 + wm + i * 16 + q4 * 4 + r;       // b*2048 + s
        int n = nl0 + wn + j * 16 + c;               // h*64 + d (within 1024)
        if (z == 0) {
          Q[(size_t)m * 1024 + n] = f2bf(acc[i][j][r] * QSCALE);
        } else if (z == 1) {
          K[(size_t)m * 1024 + n] = f2bf(acc[i][j][r]);
        } else {
          int b = m >> 11, s = m & 2047, h = n >> 6, d = n & 63;
          int kv = s & 127;
          int sig = ((kv >> 5) << 5) | (((kv >> 2) & 3) << 3) | (((kv >> 4) & 1) << 2) | (kv & 3);
          int sp = (s & ~127) | sig;
          Vt[(((size_t)(b * 16 + h) * 64 + d) << 11) + sp] = f2bf(acc[i][j][r]);
        }
      }
}

// ---------- flash attention, kv-split=2, fixed-max streaming softmax ----------
// grid (16 qt, 32 bh, 2 z). Block z handles k-tiles z*8..z*8+8, writes bf16 partial
// numerator On[z] (O layout) and fp32 partial denominator L[z][(b*2048+s)*16+h].
__global__ void __launch_bounds__(256, 2) attn(const u16* __restrict__ Q, const u16* __restrict__ K,
                                               const u16* __restrict__ Vt,
                                               u16* __restrict__ On0, u16* __restrict__ On1,
                                               float* __restrict__ L0, float* __restrict__ L1) {
  __shared__ u16 Ks[128 * 64];   // [kv 128][d 64], swizzled (8 chunks/row)
  __shared__ u16 Vs[64 * 128];   // [d 64][kv' 128], swizzled (16 chunks/row)

  const int tid = threadIdx.x, w = tid >> 6, lane = tid & 63;
  const int q4 = lane >> 4, c = lane & 15;
  const int qt = blockIdx.x;                 // 0..15
  const int bh = blockIdx.y;                 // 0..31
  const int z  = blockIdx.z;                 // 0..1
  const int b = bh >> 4, h = bh & 15;
  u16* __restrict__ On = z ? On1 : On0;
  float* __restrict__ Lz = z ? L1 : L0;

  const size_t qkbase = ((size_t)b * 2048) * 1024 + h * 64;   // [B,S,H,dh]
  const size_t vtbase = ((size_t)(b * 16 + h) * 64) * 2048;   // [B,H,dh,S']
  const int qbase = qt * 128 + w * 32;

  bf16x8 qf[2][2];
#pragma unroll
  for (int t2 = 0; t2 < 2; ++t2)
#pragma unroll
    for (int ks = 0; ks < 2; ++ks)
      qf[t2][ks] = *(const bf16x8*)(Q + qkbase + (size_t)(qbase + t2 * 16 + c) * 1024 +
                                    ks * 32 + q4 * 8);

  float lpart[2] = {0.f, 0.f};
  f32x4 oacc[2][4];
#pragma unroll
  for (int t2 = 0; t2 < 2; ++t2)
#pragma unroll
    for (int dt = 0; dt < 4; ++dt) { f32x4 zv = {0.f, 0.f, 0.f, 0.f}; oacc[t2][dt] = zv; }

  int krow[4], klc[4], vrow[4], vlc[4];
#pragma unroll
  for (int i = 0; i < 4; ++i) {
    int ci = i * 256 + w * 64 + lane;
    krow[i] = ci >> 3; klc[i] = ((ci & 7) ^ (krow[i] & 7)) * 8;
    vrow[i] = ci >> 4; vlc[i] = ((ci & 15) ^ (vrow[i] & 15)) * 8;
  }

  for (int kt = z * 8; kt < z * 8 + 8; ++kt) {
    __syncthreads();
#pragma unroll
    for (int i = 0; i < 4; ++i) {
      gl_lds16(K + qkbase + (size_t)(kt * 128 + krow[i]) * 1024 + klc[i],
               Ks + (i * 256 + w * 64) * 8);
      gl_lds16(Vt + vtbase + (size_t)vrow[i] * 2048 + kt * 128 + vlc[i],
               Vs + (i * 256 + w * 64) * 8);
    }
    __syncthreads();

    f32x4 sacc[2][8];
#pragma unroll
    for (int t2 = 0; t2 < 2; ++t2)
#pragma unroll
      for (int a = 0; a < 8; ++a) { f32x4 iv = {-M0, -M0, -M0, -M0}; sacc[t2][a] = iv; }
#pragma unroll
    for (int ks = 0; ks < 2; ++ks) {
#pragma unroll
      for (int a = 0; a < 8; ++a) {
        bf16x8 kf = *(const bf16x8*)(Ks + (a * 16 + c) * 64 + (((ks * 4 + q4) ^ (c & 7)) * 8));
        sacc[0][a] = __builtin_amdgcn_mfma_f32_16x16x32_bf16(kf, qf[0][ks], sacc[0][a], 0, 0, 0);
        sacc[1][a] = __builtin_amdgcn_mfma_f32_16x16x32_bf16(kf, qf[1][ks], sacc[1][a], 0, 0, 0);
      }
    }

    u32 pk[2][8][2];
#pragma unroll
    for (int t2 = 0; t2 < 2; ++t2) {
      float rs = 0.f;
#pragma unroll
      for (int a = 0; a < 8; ++a) {
        FU p0, p1, p2, p3;
        p0.f = __builtin_amdgcn_exp2f(sacc[t2][a][0]);
        p1.f = __builtin_amdgcn_exp2f(sacc[t2][a][1]);
        p2.f = __builtin_amdgcn_exp2f(sacc[t2][a][2]);
        p3.f = __builtin_amdgcn_exp2f(sacc[t2][a][3]);
        FU t0, t1, t2u, t3;
        t0.u = p0.u & 0xFFFF0000u; t1.u = p1.u & 0xFFFF0000u;
        t2u.u = p2.u & 0xFFFF0000u; t3.u = p3.u & 0xFFFF0000u;
        rs += (t0.f + t1.f) + (t2u.f + t3.f);
        pk[t2][a][0] = __builtin_amdgcn_perm(p1.u, p0.u, 0x07060302u);
        pk[t2][a][1] = __builtin_amdgcn_perm(p3.u, p2.u, 0x07060302u);
      }
      lpart[t2] += rs;
    }

#pragma unroll
    for (int kch = 0; kch < 4; ++kch) {
      BF8 pf0, pf1;
      pf0.u[0] = pk[0][2 * kch][0];     pf0.u[1] = pk[0][2 * kch][1];
      pf0.u[2] = pk[0][2 * kch + 1][0]; pf0.u[3] = pk[0][2 * kch + 1][1];
      pf1.u[0] = pk[1][2 * kch][0];     pf1.u[1] = pk[1][2 * kch][1];
      pf1.u[2] = pk[1][2 * kch + 1][0]; pf1.u[3] = pk[1][2 * kch + 1][1];
#pragma unroll
      for (int dt = 0; dt < 4; ++dt) {
        bf16x8 vf = *(const bf16x8*)(Vs + (dt * 16 + c) * 128 + (((kch * 4 + q4) ^ c) * 8));
        oacc[0][dt] = __builtin_amdgcn_mfma_f32_16x16x32_bf16(vf, pf0.v, oacc[0][dt], 0, 0, 0);
        oacc[1][dt] = __builtin_amdgcn_mfma_f32_16x16x32_bf16(vf, pf1.v, oacc[1][dt], 0, 0, 0);
      }
    }
  }

  // write UNNORMALIZED partial numerator (bf16) + partial denominator (fp32)
#pragma unroll
  for (int t2 = 0; t2 < 2; ++t2) {
    float l = lpart[t2];
    l += __shfl_xor(l, 16, 64);
    l += __shfl_xor(l, 32, 64);
    size_t rowbase = qkbase + (size_t)(qbase + t2 * 16 + c) * 1024;
#pragma unroll
    for (int dt = 0; dt < 4; ++dt) {
      ushort4 o;
      o.x = f2bf(oacc[t2][dt][0]);
      o.y = f2bf(oacc[t2][dt][1]);
      o.z = f2bf(oacc[t2][dt][2]);
      o.w = f2bf(oacc[t2][dt][3]);
      *(ushort4*)(On + rowbase + dt * 16 + q4 * 4) = o;
    }
    if (lane < 16)
      Lz[((size_t)(b * 2048 + qbase + t2 * 16 + lane)) * 16 + h] = l;
  }
}

// ---------- combine: Ow = (On0 + On1) / (L0 + L1), in-place over On0 ----------
__global__ void __launch_bounds__(256) attn_combine(u16* __restrict__ On0,
                                                    const u16* __restrict__ On1,
                                                    const float* __restrict__ L0,
                                                    const float* __restrict__ L1) {
  int e = (blockIdx.x * 256 + threadIdx.x) * 8;
  uint4 a = *(const uint4*)(On0 + e);
  uint4 bb = *(const uint4*)(On1 + e);
  float inv = 1.0f / (L0[e >> 6] + L1[e >> 6]);
  u32 au[4] = {a.x, a.y, a.z, a.w}, bu[4] = {bb.x, bb.y, bb.z, bb.w};
  u16 o[8];
#pragma unroll
  for (int j = 0; j < 4; ++j) {
    FU f0l, f0h, f1l, f1h;
    f0l.u = (au[j] & 0xFFFFu) << 16; f0h.u = au[j] & 0xFFFF0000u;
    f1l.u = (bu[j] & 0xFFFFu) << 16; f1h.u = bu[j] & 0xFFFF0000u;
    o[2 * j]     = f2bf((f0l.f + f1l.f) * inv);
    o[2 * j + 1] = f2bf((f0h.f + f1h.f) * inv);
  }
  *(uint4*)(On0 + e) = *(uint4*)o;
}

// ---------- final projection: out = O @ Wo^T + bo (fp32 out), tile 128x64 ----------
__global__ void __launch_bounds__(256) out_gemm(const u16* __restrict__ A, const u16* __restrict__ W,
                                                const float* __restrict__ bias,
                                                float* __restrict__ Cout) {
  __shared__ u16 As[128 * 64];
  __shared__ u16 Bs[64 * 64];
  f32x4 acc[4][2];
#pragma unroll
  for (int i = 0; i < 4; ++i)
#pragma unroll
    for (int j = 0; j < 2; ++j) { f32x4 zv = {0.f, 0.f, 0.f, 0.f}; acc[i][j] = zv; }

  const int m0 = blockIdx.y * 128, n0 = blockIdx.x * 64;
  gemm_core_t<128, 64>(A, W, As, Bs, acc, m0, n0);

  const int tid = threadIdx.x, w = tid >> 6, lane = tid & 63;
  const int wm = (w >> 1) * 64, wn = (w & 1) * 32;
  const int q4 = lane >> 4, c = lane & 15;
#pragma unroll
  for (int j = 0; j < 2; ++j) {
    int n = n0 + wn + j * 16 + c;
    float bv = bias[n];
#pragma unroll
    for (int i = 0; i < 4; ++i)
#pragma unroll
      for (int r = 0; r < 4; ++r) {
        int m = m0 + wm + i * 16 + q4 * 4 + r;
        Cout[(size_t)m * 1024 + n] = acc[i][j][r] + bv;
      }
  }
}

// ---------- launch ----------
extern "C" void kernel_launch(void* const* d_in, const int* in_sizes, int n_in,
                              void* d_out, int out_size, void* d_ws, size_t ws_size,
                              hipStream_t stream) {
  const float* hs = (const float*)d_in[0];
  const float* Wq = (const float*)d_in[1];
  const float* Wk = (const float*)d_in[2];
  const float* Wv = (const float*)d_in[3];
  const float* Wo = (const float*)d_in[4];
  const float* bo = (const float*)d_in[5];
  float* out = (float*)d_out;

  u16* Hb   = (u16*)d_ws;            // 4M u16 — dead after qkv, reused as On1
  u16* Wqkv = Hb + 4096 * 1024;      // 3M u16 — dead after qkv, reused as L0/L1
  u16* Wob  = Wqkv + 3 * 1024 * 1024;
  u16* Qw   = Wob + 1024 * 1024;     // [B,S,H,dh], pre-scaled by QSCALE
  u16* Kw   = Qw + 4096 * 1024;      // [B,S,H,dh]
  u16* Vtw  = Kw + 4096 * 1024;      // [B,H,dh,S'] sigma-permuted
  u16* Ow   = Vtw + 4096 * 1024;     // On0 partial -> combined O (in-place)

  u16* On1  = Hb;                    // overlay (Hb dead after qkv_gemm)
  float* L0 = (float*)Wqkv;          // overlay (Wqkv dead after qkv_gemm)
  float* L1 = L0 + 65536;

  cvt_f32_bf16<<<4096, 256, 0, stream>>>(hs, Hb, 4096 * 1024);
  cvt_w4<<<4096, 256, 0, stream>>>(Wq, Wk, Wv, Wo, Wqkv);   // Wob = Wqkv + 3M

  qkv_gemm<<<dim3(24, 32), 256, 0, stream>>>(Hb, Wqkv, Qw, Kw, Vtw);
  attn<<<dim3(16, 32, 2), 256, 0, stream>>>(Qw, Kw, Vtw, Ow, On1, L0, L1);
  attn_combine<<<2048, 256, 0, stream>>>(Ow, On1, L0, L1);
  out_gemm<<<dim3(16, 32), 256, 0, stream>>>(Ow, Wob, bo, out);
}

// Round 9
// 199.410 us; speedup vs baseline: 1.7549x; 1.0729x over previous
//
#include <hip/hip_runtime.h>
#include <stdint.h>

typedef unsigned short u16;
typedef unsigned int u32;
typedef __bf16 bf16x8 __attribute__((ext_vector_type(8)));
typedef float f32x4 __attribute__((ext_vector_type(4)));

#define QSCALE 0.1803368801111244f   // 64^-0.5 * log2(e): S comes out in log2 domain
#define M0 18.0f                     // fixed softmax "max" in log2 domain (true |s| <~ 12)

// ---------- helpers ----------
__device__ __forceinline__ u16 f2bf(float f) {
  union { float f; unsigned u; } v; v.f = f;
  return (u16)((v.u + 0x7FFFu + ((v.u >> 16) & 1u)) >> 16);
}

__device__ __forceinline__ void gl_lds16(const void* g, void* l) {
  typedef __attribute__((address_space(1))) void* gp_t;
  typedef __attribute__((address_space(3))) void* lp_t;
  __builtin_amdgcn_global_load_lds((gp_t)(g), (lp_t)(l), 16, 0, 0);
}

union BF8 { u32 u[4]; bf16x8 v; };
union FU { float f; u32 u; };

// ---------- fp32 -> bf16 converts ----------
__global__ void __launch_bounds__(256) cvt_f32_bf16(const float* __restrict__ in,
                                                    u16* __restrict__ out, int n) {
  int i = (blockIdx.x * 256 + threadIdx.x) * 4;
  if (i < n) {
    float4 f = *(const float4*)(in + i);
    ushort4 o;
    o.x = f2bf(f.x); o.y = f2bf(f.y); o.z = f2bf(f.z); o.w = f2bf(f.w);
    *(ushort4*)(out + i) = o;
  }
}

// 4 weight matrices (1M elements each) -> contiguous bf16 dst
__global__ void __launch_bounds__(256) cvt_w4(const float* __restrict__ a,
                                              const float* __restrict__ b,
                                              const float* __restrict__ c,
                                              const float* __restrict__ d,
                                              u16* __restrict__ out) {
  int i = (blockIdx.x * 256 + threadIdx.x) * 4;
  int sel = i >> 20;
  const float* src = (sel == 0) ? a : (sel == 1) ? b : (sel == 2) ? c : d;
  float4 f = *(const float4*)(src + (i & 1048575));
  ushort4 o;
  o.x = f2bf(f.x); o.y = f2bf(f.y); o.z = f2bf(f.z); o.w = f2bf(f.w);
  *(uint64_t*)&o;  // no-op
  *(ushort4*)(out + i) = o;
}

// ---------- m97-style MT x NT x BK GEMM core: C = A @ W^T, K=1024 ----------
// global_load_lds width-16 staging, single-buffered LDS, 2-barrier K-loop,
// XOR-swizzled LDS: slot s of row r holds logical k-chunk s^(r&(CPR-1)).
template <int MT, int NT, int BK>
__device__ __forceinline__ void gemm_core_t(const u16* __restrict__ A, const u16* __restrict__ W,
                                            u16* As, u16* Bs,
                                            f32x4 (&acc)[MT / 32][NT / 32],
                                            int m0, int n0) {
  constexpr int FA = MT / 32, FB = NT / 32;     // frags per wave
  constexpr int CPR = BK / 8;                   // 16B chunks per LDS row
  constexpr int ALD = MT * CPR / 256;           // A staging loads per thread
  constexpr int BLD = NT * CPR / 256;
  const int tid = threadIdx.x, w = tid >> 6, lane = tid & 63;
  const int wm = (w >> 1) * (MT / 2), wn = (w & 1) * (NT / 2);
  const int q4 = lane >> 4, c = lane & 15;

  for (int k0 = 0; k0 < 1024; k0 += BK) {
#pragma unroll
    for (int g = 0; g < ALD; ++g) {
      int ci = g * 256 + tid, row = ci / CPR, kc = ci % CPR;
      gl_lds16(A + (size_t)(m0 + row) * 1024 + k0 + ((kc ^ (row & (CPR - 1))) * 8),
               As + (g * 256 + w * 64) * 8);
    }
#pragma unroll
    for (int g = 0; g < BLD; ++g) {
      int ci = g * 256 + tid, row = ci / CPR, kc = ci % CPR;
      gl_lds16(W + (size_t)(n0 + row) * 1024 + k0 + ((kc ^ (row & (CPR - 1))) * 8),
               Bs + (g * 256 + w * 64) * 8);
    }
    __syncthreads();
#pragma unroll
    for (int ks = 0; ks < BK / 32; ++ks) {
      bf16x8 af[FA], bfr[FB];
#pragma unroll
      for (int i = 0; i < FA; ++i) {
        int row = wm + i * 16 + c;
        af[i] = *(const bf16x8*)(As + row * BK + (((ks * 4 + q4) ^ (row & (CPR - 1))) * 8));
      }
#pragma unroll
      for (int j = 0; j < FB; ++j) {
        int row = wn + j * 16 + c;
        bfr[j] = *(const bf16x8*)(Bs + row * BK + (((ks * 4 + q4) ^ (row & (CPR - 1))) * 8));
      }
#pragma unroll
      for (int i = 0; i < FA; ++i)
#pragma unroll
        for (int j = 0; j < FB; ++j)
          acc[i][j] = __builtin_amdgcn_mfma_f32_16x16x32_bf16(af[i], bfr[j], acc[i][j], 0, 0, 0);
    }
    __syncthreads();
  }
}

// ---------- fused QKV projection: one GEMM vs [Wq;Wk;Wv] (N=3072), tile 128x128x128 ----------
__global__ void __launch_bounds__(256) qkv_gemm(const u16* __restrict__ Hb,
                                                const u16* __restrict__ Wqkv,
                                                u16* __restrict__ Q, u16* __restrict__ K,
                                                u16* __restrict__ Vt) {
  __shared__ u16 As[128 * 128];   // 32 KiB
  __shared__ u16 Bs[128 * 128];   // 32 KiB
  f32x4 acc[4][4];
#pragma unroll
  for (int i = 0; i < 4; ++i)
#pragma unroll
    for (int j = 0; j < 4; ++j) { f32x4 zv = {0.f, 0.f, 0.f, 0.f}; acc[i][j] = zv; }

  const int m0 = blockIdx.y * 128, n0g = blockIdx.x * 128;
  gemm_core_t<128, 128, 128>(Hb, Wqkv, As, Bs, acc, m0, n0g);

  const int z = n0g >> 10, nl0 = n0g & 1023;
  const int tid = threadIdx.x, w = tid >> 6, lane = tid & 63;
  const int wm = (w >> 1) * 64, wn = (w & 1) * 64;
  const int q4 = lane >> 4, c = lane & 15;

#pragma unroll
  for (int i = 0; i < 4; ++i)
#pragma unroll
    for (int j = 0; j < 4; ++j)
#pragma unroll
      for (int r = 0; r < 4; ++r) {
        int m = m0 + wm + i * 16 + q4 * 4 + r;       // b*2048 + s
        int n = nl0 + wn + j * 16 + c;               // h*64 + d (within 1024)
        if (z == 0) {
          Q[(size_t)m * 1024 + n] = f2bf(acc[i][j][r] * QSCALE);
        } else if (z == 1) {
          K[(size_t)m * 1024 + n] = f2bf(acc[i][j][r]);
        } else {
          int b = m >> 11, s = m & 2047, h = n >> 6, d = n & 63;
          int kv = s & 127;
          int sig = ((kv >> 5) << 5) | (((kv >> 2) & 3) << 3) | (((kv >> 4) & 1) << 2) | (kv & 3);
          int sp = (s & ~127) | sig;
          Vt[(((size_t)(b * 16 + h) * 64 + d) << 11) + sp] = f2bf(acc[i][j][r]);
        }
      }
}

// ---------- flash attention: 512 threads = 8 waves, 256 q per block ----------
// K/V staged once per 256 q (halves staging bytes vs 128-q blocks); kv-tiles staged
// in PAIRS per barrier (64 KiB LDS, 8 barrier-iters). Fixed-max streaming softmax,
// P in registers (sigma-permuted V^T), per-lane l accumulated, one reduction at end.
__global__ void __launch_bounds__(512) attn(const u16* __restrict__ Q, const u16* __restrict__ K,
                                            const u16* __restrict__ Vt, u16* __restrict__ O) {
  __shared__ u16 Ks[2][128 * 64];   // [pair][kv 128][d 64], swizzled (8 chunks/row)
  __shared__ u16 Vs[2][64 * 128];   // [pair][d 64][kv' 128], swizzled (16 chunks/row)

  const int tid = threadIdx.x, w = tid >> 6, lane = tid & 63;   // w = 0..7
  const int q4 = lane >> 4, c = lane & 15;
  const int qt = blockIdx.x;                 // 0..7  (256 q each)
  const int bh = blockIdx.y;                 // 0..31
  const int b = bh >> 4, h = bh & 15;

  const size_t qkbase = ((size_t)b * 2048) * 1024 + h * 64;   // [B,S,H,dh]
  const size_t vtbase = ((size_t)(b * 16 + h) * 64) * 2048;   // [B,H,dh,S']
  const int qbase = qt * 256 + w * 32;

  // Q fragments (B-operand: n=q=c, k=d=q4*8+j), resident all kernel
  bf16x8 qf[2][2];
#pragma unroll
  for (int t2 = 0; t2 < 2; ++t2)
#pragma unroll
    for (int ks = 0; ks < 2; ++ks)
      qf[t2][ks] = *(const bf16x8*)(Q + qkbase + (size_t)(qbase + t2 * 16 + c) * 1024 +
                                    ks * 32 + q4 * 8);

  float lpart[2] = {0.f, 0.f};
  f32x4 oacc[2][4];
#pragma unroll
  for (int t2 = 0; t2 < 2; ++t2)
#pragma unroll
    for (int dt = 0; dt < 4; ++dt) { f32x4 zv = {0.f, 0.f, 0.f, 0.f}; oacc[t2][dt] = zv; }

  // staging indices: 512 threads, per kv-tile 1024 K-chunks + 1024 V-chunks -> 2 each
  int krow[2], klc[2], vrow[2], vlc[2];
#pragma unroll
  for (int i = 0; i < 2; ++i) {
    int ci = i * 512 + tid;
    krow[i] = ci >> 3; klc[i] = ((ci & 7) ^ (krow[i] & 7)) * 8;
    vrow[i] = ci >> 4; vlc[i] = ((ci & 15) ^ (vrow[i] & 15)) * 8;
  }

  for (int kt2 = 0; kt2 < 8; ++kt2) {
    __syncthreads();
#pragma unroll
    for (int j = 0; j < 2; ++j) {
      int kt = kt2 * 2 + j;
#pragma unroll
      for (int i = 0; i < 2; ++i) {
        gl_lds16(K + qkbase + (size_t)(kt * 128 + krow[i]) * 1024 + klc[i],
                 Ks[j] + (i * 512 + w * 64) * 8);
        gl_lds16(Vt + vtbase + (size_t)vrow[i] * 2048 + kt * 128 + vlc[i],
                 Vs[j] + (i * 512 + w * 64) * 8);
      }
    }
    __syncthreads();

#pragma unroll
    for (int j = 0; j < 2; ++j) {
      // S^T - M0 = K Q^T - M0 : C[row=kv (q4*4+r), col=q=c], log2 domain
      f32x4 sacc[2][8];
#pragma unroll
      for (int t2 = 0; t2 < 2; ++t2)
#pragma unroll
        for (int a = 0; a < 8; ++a) { f32x4 iv = {-M0, -M0, -M0, -M0}; sacc[t2][a] = iv; }
#pragma unroll
      for (int ks = 0; ks < 2; ++ks) {
#pragma unroll
        for (int a = 0; a < 8; ++a) {
          bf16x8 kf = *(const bf16x8*)(Ks[j] + (a * 16 + c) * 64 + (((ks * 4 + q4) ^ (c & 7)) * 8));
          sacc[0][a] = __builtin_amdgcn_mfma_f32_16x16x32_bf16(kf, qf[0][ks], sacc[0][a], 0, 0, 0);
          sacc[1][a] = __builtin_amdgcn_mfma_f32_16x16x32_bf16(kf, qf[1][ks], sacc[1][a], 0, 0, 0);
        }
      }

      // p = exp2(sacc); truncate to bf16; accumulate l from truncated values
      u32 pk[2][8][2];
#pragma unroll
      for (int t2 = 0; t2 < 2; ++t2) {
        float rs = 0.f;
#pragma unroll
        for (int a = 0; a < 8; ++a) {
          FU p0, p1, p2, p3;
          p0.f = __builtin_amdgcn_exp2f(sacc[t2][a][0]);
          p1.f = __builtin_amdgcn_exp2f(sacc[t2][a][1]);
          p2.f = __builtin_amdgcn_exp2f(sacc[t2][a][2]);
          p3.f = __builtin_amdgcn_exp2f(sacc[t2][a][3]);
          FU t0, t1, t2u, t3;
          t0.u = p0.u & 0xFFFF0000u; t1.u = p1.u & 0xFFFF0000u;
          t2u.u = p2.u & 0xFFFF0000u; t3.u = p3.u & 0xFFFF0000u;
          rs += (t0.f + t1.f) + (t2u.f + t3.f);
          pk[t2][a][0] = __builtin_amdgcn_perm(p1.u, p0.u, 0x07060302u);
          pk[t2][a][1] = __builtin_amdgcn_perm(p3.u, p2.u, 0x07060302u);
        }
        lpart[t2] += rs;
      }

      // O^T += V^T P^T : A = V^T (m=d), B = P^T straight from pk registers
#pragma unroll
      for (int kch = 0; kch < 4; ++kch) {
        BF8 pf0, pf1;
        pf0.u[0] = pk[0][2 * kch][0];     pf0.u[1] = pk[0][2 * kch][1];
        pf0.u[2] = pk[0][2 * kch + 1][0]; pf0.u[3] = pk[0][2 * kch + 1][1];
        pf1.u[0] = pk[1][2 * kch][0];     pf1.u[1] = pk[1][2 * kch][1];
        pf1.u[2] = pk[1][2 * kch + 1][0]; pf1.u[3] = pk[1][2 * kch + 1][1];
#pragma unroll
        for (int dt = 0; dt < 4; ++dt) {
          bf16x8 vf = *(const bf16x8*)(Vs[j] + (dt * 16 + c) * 128 + (((kch * 4 + q4) ^ c) * 8));
          oacc[0][dt] = __builtin_amdgcn_mfma_f32_16x16x32_bf16(vf, pf0.v, oacc[0][dt], 0, 0, 0);
          oacc[1][dt] = __builtin_amdgcn_mfma_f32_16x16x32_bf16(vf, pf1.v, oacc[1][dt], 0, 0, 0);
        }
      }
    }
  }

  // single deferred l reduction, then normalize + store O [B,S,H,dh]
#pragma unroll
  for (int t2 = 0; t2 < 2; ++t2) {
    float l = lpart[t2];
    l += __shfl_xor(l, 16, 64);
    l += __shfl_xor(l, 32, 64);
    float inv = 1.0f / l;
    size_t rowbase = qkbase + (size_t)(qbase + t2 * 16 + c) * 1024;
#pragma unroll
    for (int dt = 0; dt < 4; ++dt) {
      ushort4 o;
      o.x = f2bf(oacc[t2][dt][0] * inv);
      o.y = f2bf(oacc[t2][dt][1] * inv);
      o.z = f2bf(oacc[t2][dt][2] * inv);
      o.w = f2bf(oacc[t2][dt][3] * inv);
      *(ushort4*)(O + rowbase + dt * 16 + q4 * 4) = o;
    }
  }
}

// ---------- final projection: out = O @ Wo^T + bo (fp32 out), tile 128x64x128 ----------
__global__ void __launch_bounds__(256) out_gemm(const u16* __restrict__ A, const u16* __restrict__ W,
                                                const float* __restrict__ bias,
                                                float* __restrict__ Cout) {
  __shared__ u16 As[128 * 128];   // 32 KiB
  __shared__ u16 Bs[64 * 128];    // 16 KiB
  f32x4 acc[4][2];
#pragma unroll
  for (int i = 0; i < 4; ++i)
#pragma unroll
    for (int j = 0; j < 2; ++j) { f32x4 zv = {0.f, 0.f, 0.f, 0.f}; acc[i][j] = zv; }

  const int m0 = blockIdx.y * 128, n0 = blockIdx.x * 64;
  gemm_core_t<128, 64, 128>(A, W, As, Bs, acc, m0, n0);

  const int tid = threadIdx.x, w = tid >> 6, lane = tid & 63;
  const int wm = (w >> 1) * 64, wn = (w & 1) * 32;
  const int q4 = lane >> 4, c = lane & 15;
#pragma unroll
  for (int j = 0; j < 2; ++j) {
    int n = n0 + wn + j * 16 + c;
    float bv = bias[n];
#pragma unroll
    for (int i = 0; i < 4; ++i)
#pragma unroll
      for (int r = 0; r < 4; ++r) {
        int m = m0 + wm + i * 16 + q4 * 4 + r;
        Cout[(size_t)m * 1024 + n] = acc[i][j][r] + bv;
      }
  }
}

// ---------- launch ----------
extern "C" void kernel_launch(void* const* d_in, const int* in_sizes, int n_in,
                              void* d_out, int out_size, void* d_ws, size_t ws_size,
                              hipStream_t stream) {
  const float* hs = (const float*)d_in[0];
  const float* Wq = (const float*)d_in[1];
  const float* Wk = (const float*)d_in[2];
  const float* Wv = (const float*)d_in[3];
  const float* Wo = (const float*)d_in[4];
  const float* bo = (const float*)d_in[5];
  float* out = (float*)d_out;

  u16* Hb   = (u16*)d_ws;            // 4096*1024
  u16* Wqkv = Hb + 4096 * 1024;      // [3072,1024]: Wq, Wk, Wv contiguous
  u16* Wob  = Wqkv + 3 * 1024 * 1024;
  u16* Qw   = Wob + 1024 * 1024;     // [B,S,H,dh], pre-scaled by QSCALE
  u16* Kw   = Qw + 4096 * 1024;      // [B,S,H,dh]
  u16* Vtw  = Kw + 4096 * 1024;      // [B,H,dh,S'] sigma-permuted
  u16* Ow   = Vtw + 4096 * 1024;     // [B,S,H,dh]

  cvt_f32_bf16<<<4096, 256, 0, stream>>>(hs, Hb, 4096 * 1024);
  cvt_w4<<<4096, 256, 0, stream>>>(Wq, Wk, Wv, Wo, Wqkv);   // Wob = Wqkv + 3M

  qkv_gemm<<<dim3(24, 32), 256, 0, stream>>>(Hb, Wqkv, Qw, Kw, Vtw);
  attn<<<dim3(8, 32), 512, 0, stream>>>(Qw, Kw, Vtw, Ow);
  out_gemm<<<dim3(16, 32), 256, 0, stream>>>(Ow, Wob, bo, out);
}